// Round 2
// baseline (314.627 us; speedup 1.0000x reference)
//
#include <hip/hip_runtime.h>
#include <math.h>

#define HIDDEN 128
#define MAIN_BLOCKS 512
#define MAIN_THREADS 1024
#define MAX_BMAP_WORDS 6272   // 200704 bits >= 200000 nodes
#define FLAG_MAGIC 0x13579BDFu

// ---------------------------------------------------------------------------
// Single fused kernel (512 blocks x 1024 threads):
//   per block:  q = [x ; X[start] ; X[prev]] @ Wq  (redundant, L2-broadcast)
//               qk = (Wk @ q)/sqrt(128)            (in LDS)
//               streaming online softmax + weighted X sum over its row slice
//               publish (Mb,Sb,Gb) with device-scope release + sentinel flags
//   block 511:  acquire-spin on all 512 sentinel pairs, then merge partials,
//               pvec@Wv@Wo -> out.  No second dispatch.
// Sentinel pair (MAGIC, ~MAGIC) is init-free: no uniform poison P satisfies
// P==MAGIC && P==~MAGIC (needs P==~P). Publish is the rocPRIM decoupled-
// lookback pattern: stores -> __threadfence (per thread) -> __syncthreads ->
// release-atomic flag store; reader uses agent-scope acquire loads (G16).
// ---------------------------------------------------------------------------
__global__ __launch_bounds__(MAIN_THREADS) void fused_all(
    const float* __restrict__ X, const float* __restrict__ x,
    const float* __restrict__ Wq, const float* __restrict__ Wk,
    const float* __restrict__ Wv, const float* __restrict__ Wo,
    const int* __restrict__ visited, int nv,
    const int* __restrict__ startp, const int* __restrict__ prevp,
    float* __restrict__ Mb, float* __restrict__ Sb, float* __restrict__ Gb,
    unsigned* __restrict__ flagA, unsigned* __restrict__ flagB,
    float* __restrict__ out, int n)
{
    __shared__ unsigned bmap[MAX_BMAP_WORDS];   // 25088 B
    __shared__ float fc[384];
    __shared__ float qpart[8][HIDDEN];          // 4 KB (reused by finisher)
    __shared__ float qv[HIDDEN];                // q, later pvec
    __shared__ float qks[HIDDEN];               // qk, later hvec
    __shared__ float m_arr[32];
    __shared__ float s_arr[32];
    __shared__ float g_all[32 * HIDDEN];        // 16 KB
    __shared__ float fin_red[MAIN_THREADS];     // 4 KB (finisher reductions)
    __shared__ float fin_e[MAIN_BLOCKS];        // 2 KB
    // total ~53.3 KB -> LDS allows 2 blocks/CU

    const int tid  = threadIdx.x;
    const int lane = tid & 63;
    const int sub  = lane & 31;
    const int half = (lane >> 5) & 1;

    // ---- Phase 0: issue fc global loads early, zero bitmap meanwhile ----
    const int nwords = (n + 31) >> 5;
    float fcv = 0.f;
    if (tid < 384) {
        if (tid < 128)      fcv = x[tid];
        else if (tid < 256) fcv = X[(size_t)startp[0] * HIDDEN + (tid - 128)];
        else                fcv = X[(size_t)prevp[0]  * HIDDEN + (tid - 256)];
    }
    for (int w = tid; w < nwords; w += MAIN_THREADS) bmap[w] = 0u;
    if (tid < 384) fc[tid] = fcv;
    __syncthreads();

    // ---- Phase 1: visited scatter (dup-safe) + q partials (q = fc @ Wq) ----
    for (int i = tid; i < nv; i += MAIN_THREADS) {
        const int v = visited[i];
        atomicOr(&bmap[v >> 5], 1u << (v & 31));
    }
    {
        const int col = tid & (HIDDEN - 1);
        const int seg = tid >> 7;              // 0..7, 48 m-rows each
        const int m0  = seg * 48;
        float acc = 0.f;
        #pragma unroll 8
        for (int m = 0; m < 48; ++m)
            acc += fc[m0 + m] * Wq[(size_t)(m0 + m) * HIDDEN + col];
        qpart[seg][col] = acc;
    }
    __syncthreads();
    if (tid < HIDDEN)
        qv[tid] = ((qpart[0][tid] + qpart[1][tid]) + (qpart[2][tid] + qpart[3][tid]))
                + ((qpart[4][tid] + qpart[5][tid]) + (qpart[6][tid] + qpart[7][tid]));
    __syncthreads();

    // ---- Phase 2: qk rows; 32 half-waves x 4 rows, coalesced float4 ----
    {
        const int hw0 = tid >> 5;              // 0..31
        const float4 qv4 = *(const float4*)(&qv[sub << 2]);
        #pragma unroll
        for (int k = 0; k < 4; ++k) {
            const int row = hw0 + (k << 5);
            const float4 wk4 = *(const float4*)(Wk + (size_t)row * HIDDEN + (sub << 2));
            float p = wk4.x * qv4.x + wk4.y * qv4.y + wk4.z * qv4.z + wk4.w * qv4.w;
            #pragma unroll
            for (int off = 16; off >= 1; off >>= 1)
                p += __shfl_xor(p, off, 64);   // off<=16 stays within 32-lane half
            if (sub == 0) qks[row] = p * 0.08838834764831845f;
        }
    }
    __syncthreads();

    // ---- Phase 3: streaming online softmax + weighted sum over X ----
    const int wavesPerBlock = MAIN_THREADS >> 6;          // 16
    const int gw  = blockIdx.x * wavesPerBlock + (tid >> 6);
    const int vhw = gw * 2 + half;
    const int T   = gridDim.x * wavesPerBlock * 2;        // 16384 half-waves

    const float4 qkv = *(const float4*)(&qks[sub << 2]);

    float m = -INFINITY, s = 0.f;
    float g0 = 0.f, g1 = 0.f, g2 = 0.f, g3 = 0.f;

    for (int r = vhw; r < n; r += T) {
        const float4 xv = *(const float4*)(X + (size_t)r * HIDDEN + (sub << 2));
        float p = xv.x * qkv.x + xv.y * qkv.y + xv.z * qkv.z + xv.w * qkv.w;
        #pragma unroll
        for (int off = 16; off >= 1; off >>= 1)
            p += __shfl_xor(p, off, 64);
        const float maskv = ((bmap[r >> 5] >> (r & 31)) & 1u) ? 0.f : 1.f;
        const float u  = p + maskv;
        const float mn    = fmaxf(m, u);
        const float scale = __expf(m - mn);   // exp(-inf)=0 on first iter
        const float w     = __expf(u - mn);
        s  = s  * scale + w;
        g0 = g0 * scale + w * xv.x;
        g1 = g1 * scale + w * xv.y;
        g2 = g2 * scale + w * xv.z;
        g3 = g3 * scale + w * xv.w;
        m  = mn;
    }

    // ---- block combine: 32 half-waves -> 1 partial ----
    const int hw = tid >> 5;
    *(float4*)(&g_all[hw * HIDDEN + (sub << 2)]) = make_float4(g0, g1, g2, g3);
    if (sub == 0) { m_arr[hw] = m; s_arr[hw] = s; }
    __syncthreads();

    float mb = m_arr[0];
    #pragma unroll
    for (int h = 1; h < 32; ++h) mb = fmaxf(mb, m_arr[h]);

    if (tid < HIDDEN) {
        float G = 0.f;
        #pragma unroll 4
        for (int h = 0; h < 32; ++h)
            G += g_all[h * HIDDEN + tid] * __expf(m_arr[h] - mb);
        Gb[blockIdx.x * HIDDEN + tid] = G;
    } else if (tid == HIDDEN) {
        float S = 0.f;
        #pragma unroll
        for (int h = 0; h < 32; ++h) S += s_arr[h] * __expf(m_arr[h] - mb);
        Sb[blockIdx.x] = S;
        Mb[blockIdx.x] = mb;
    }

    // ---- Publish: release partials device-wide, set sentinel pair ----
    __threadfence();                            // device-scope release fence
    __syncthreads();
    if (tid == 0) {
        __hip_atomic_store(&flagA[blockIdx.x], FLAG_MAGIC,
                           __ATOMIC_RELEASE, __HIP_MEMORY_SCOPE_AGENT);
        __hip_atomic_store(&flagB[blockIdx.x], ~FLAG_MAGIC,
                           __ATOMIC_RELEASE, __HIP_MEMORY_SCOPE_AGENT);
    }

    if (blockIdx.x != MAIN_BLOCKS - 1) return;

    // =======================================================================
    // Finisher (block 511): wait for all 512 sentinel pairs, merge, GEMVs.
    // =======================================================================
    if (tid < MAIN_BLOCKS) {
        while (__hip_atomic_load(&flagA[tid], __ATOMIC_ACQUIRE,
                                 __HIP_MEMORY_SCOPE_AGENT) != FLAG_MAGIC ||
               __hip_atomic_load(&flagB[tid], __ATOMIC_ACQUIRE,
                                 __HIP_MEMORY_SCOPE_AGENT) != ~FLAG_MAGIC) {
            __builtin_amdgcn_s_sleep(2);
        }
    }
    __syncthreads();
    __threadfence();   // belt-and-braces acquire ordering for the whole block

    // global max over 512 block maxima
    const float mt = (tid < MAIN_BLOCKS) ? Mb[tid] : -INFINITY;
    fin_red[tid] = mt; __syncthreads();
    for (int st = 512; st >= 1; st >>= 1) {
        if (tid < st) fin_red[tid] = fmaxf(fin_red[tid], fin_red[tid + st]);
        __syncthreads();
    }
    const float M = fin_red[0];
    __syncthreads();

    // per-block scale + global softmax denominator
    float ls = 0.f;
    if (tid < MAIN_BLOCKS) {
        const float eb = __expf(mt - M); fin_e[tid] = eb; ls = Sb[tid] * eb;
    }
    fin_red[tid] = ls; __syncthreads();
    for (int st = 512; st >= 1; st >>= 1) {
        if (tid < st) fin_red[tid] += fin_red[tid + st];
        __syncthreads();
    }
    const float S = fin_red[0];
    __syncthreads();

    const int col = tid & (HIDDEN - 1);
    const int seg = tid >> 7;               // 0..7

    // pvec[col] = sum_b Gb[b,col]*e[b] / S ; 8 segments x 64 blocks
    {
        const int b0 = seg * (MAIN_BLOCKS / 8);
        float acc = 0.f;
        #pragma unroll 8
        for (int b = 0; b < MAIN_BLOCKS / 8; ++b)
            acc += Gb[(size_t)(b0 + b) * HIDDEN + col] * fin_e[b0 + b];
        qpart[seg][col] = acc;
    }
    __syncthreads();
    if (tid < HIDDEN)
        qv[tid] = (((qpart[0][tid] + qpart[1][tid]) + (qpart[2][tid] + qpart[3][tid]))
                 + ((qpart[4][tid] + qpart[5][tid]) + (qpart[6][tid] + qpart[7][tid]))) / S;
    __syncthreads();

    // h[col] = sum_m pvec[m]*Wv[m,col] ; 8 segments x 16 rows
    {
        const int m0 = seg * 16;
        float acc = 0.f;
        #pragma unroll
        for (int m2 = 0; m2 < 16; ++m2)
            acc += qv[m0 + m2] * Wv[(size_t)(m0 + m2) * HIDDEN + col];
        qpart[seg][col] = acc;
    }
    __syncthreads();
    if (tid < HIDDEN)
        qks[tid] = ((qpart[0][tid] + qpart[1][tid]) + (qpart[2][tid] + qpart[3][tid]))
                 + ((qpart[4][tid] + qpart[5][tid]) + (qpart[6][tid] + qpart[7][tid]));
    __syncthreads();

    // out[col] = sum_m h[m]*Wo[m,col]
    {
        const int m0 = seg * 16;
        float acc = 0.f;
        #pragma unroll
        for (int m2 = 0; m2 < 16; ++m2)
            acc += qks[m0 + m2] * Wo[(size_t)(m0 + m2) * HIDDEN + col];
        qpart[seg][col] = acc;
    }
    __syncthreads();
    if (tid < HIDDEN)
        out[tid] = ((qpart[0][tid] + qpart[1][tid]) + (qpart[2][tid] + qpart[3][tid]))
                 + ((qpart[4][tid] + qpart[5][tid]) + (qpart[6][tid] + qpart[7][tid]));
}

// ---------------------------------------------------------------------------
extern "C" void kernel_launch(void* const* d_in, const int* in_sizes, int n_in,
                              void* d_out, int out_size, void* d_ws, size_t ws_size,
                              hipStream_t stream)
{
    const float* X       = (const float*)d_in[0];
    const float* x       = (const float*)d_in[1];
    const float* Wq      = (const float*)d_in[2];
    const float* Wk      = (const float*)d_in[3];
    const float* Wv      = (const float*)d_in[4];
    const float* Wo      = (const float*)d_in[5];
    const int*   visited = (const int*)d_in[6];
    const int*   startp  = (const int*)d_in[7];
    const int*   prevp   = (const int*)d_in[8];

    const int n  = in_sizes[0] / HIDDEN;   // 200000
    const int nv = in_sizes[6];            // 1024

    float* ws = (float*)d_ws;
    float*    Mb    = ws + 128;
    float*    Sb    = Mb + MAIN_BLOCKS;
    float*    Gb    = Sb + MAIN_BLOCKS;                 // MAIN_BLOCKS*128
    unsigned* flagA = (unsigned*)(Gb + (size_t)MAIN_BLOCKS * HIDDEN);
    unsigned* flagB = flagA + MAIN_BLOCKS;

    fused_all<<<MAIN_BLOCKS, MAIN_THREADS, 0, stream>>>(
        X, x, Wq, Wk, Wv, Wo, visited, nv, startp, prevp,
        Mb, Sb, Gb, flagA, flagB, (float*)d_out, n);
}

// Round 3
// 190.436 us; speedup vs baseline: 1.6521x; 1.6521x over previous
//
#include <hip/hip_runtime.h>
#include <math.h>

#define HIDDEN 128
#define MAIN_BLOCKS 512
#define MAIN_THREADS 1024
#define MAX_BMAP_WORDS 6272   // 200704 bits >= 200000 nodes
#define FLAG_MAGIC 0x13579BDFu
// 64-bit sentinel: low=MAGIC, high=~MAGIC. No uniform 32-bit poison P can
// fake it (needs P==MAGIC && P==~MAGIC), so flags are init-free in poisoned ws.
#define FLAG_PAIR ((((unsigned long long)(~FLAG_MAGIC)) << 32) | (unsigned long long)FLAG_MAGIC)

// ---------------------------------------------------------------------------
// Single fused kernel (512 blocks x 1024 threads):
//   per block:  q = [x ; X[start] ; X[prev]] @ Wq  (redundant, L2-broadcast)
//               qk = (Wk @ q)/sqrt(128)            (in LDS)
//               streaming online softmax + weighted X sum over its row slice
//               publish (Mb,Sb,Gb): stores -> __syncthreads (drains vmcnt to
//               L2 per wave) -> ONE 64-bit release-atomic flag store by tid 0
//               (single wbl2/block, the rocPRIM decoupled-lookback cost model;
//               round-2's per-thread __threadfence = 8192 simultaneous wbl2
//               was the 10x regression).
//   block 511:  wave 0 acquire-spins on the 512 sentinels (8 flags/lane),
//               __syncthreads, block-local __threadfence, then merge partials,
//               pvec@Wv@Wo -> out.  No second dispatch.
// ---------------------------------------------------------------------------
__global__ __launch_bounds__(MAIN_THREADS) void fused_all(
    const float* __restrict__ X, const float* __restrict__ x,
    const float* __restrict__ Wq, const float* __restrict__ Wk,
    const float* __restrict__ Wv, const float* __restrict__ Wo,
    const int* __restrict__ visited, int nv,
    const int* __restrict__ startp, const int* __restrict__ prevp,
    float* __restrict__ Mb, float* __restrict__ Sb, float* __restrict__ Gb,
    unsigned long long* __restrict__ flag64,
    float* __restrict__ out, int n)
{
    __shared__ unsigned bmap[MAX_BMAP_WORDS];   // 25088 B
    __shared__ float fc[384];
    __shared__ float qpart[8][HIDDEN];          // 4 KB (reused by finisher)
    __shared__ float qv[HIDDEN];                // q, later pvec
    __shared__ float qks[HIDDEN];               // qk, later hvec
    __shared__ float m_arr[32];
    __shared__ float s_arr[32];
    __shared__ float g_all[32 * HIDDEN];        // 16 KB
    __shared__ float fin_red[MAIN_THREADS];     // 4 KB (finisher reductions)
    __shared__ float fin_e[MAIN_BLOCKS];        // 2 KB
    // total ~53.4 KB -> 2 blocks/CU (wave-limited: 16 waves/block)

    const int tid  = threadIdx.x;
    const int lane = tid & 63;
    const int sub  = lane & 31;
    const int half = (lane >> 5) & 1;

    // ---- Phase 0: issue fc global loads early, zero bitmap meanwhile ----
    const int nwords = (n + 31) >> 5;
    float fcv = 0.f;
    if (tid < 384) {
        if (tid < 128)      fcv = x[tid];
        else if (tid < 256) fcv = X[(size_t)startp[0] * HIDDEN + (tid - 128)];
        else                fcv = X[(size_t)prevp[0]  * HIDDEN + (tid - 256)];
    }
    for (int w = tid; w < nwords; w += MAIN_THREADS) bmap[w] = 0u;
    if (tid < 384) fc[tid] = fcv;
    __syncthreads();

    // ---- Phase 1: visited scatter (dup-safe) + q partials (q = fc @ Wq) ----
    for (int i = tid; i < nv; i += MAIN_THREADS) {
        const int v = visited[i];
        atomicOr(&bmap[v >> 5], 1u << (v & 31));
    }
    {
        const int col = tid & (HIDDEN - 1);
        const int seg = tid >> 7;              // 0..7, 48 m-rows each
        const int m0  = seg * 48;
        float acc = 0.f;
        #pragma unroll 8
        for (int m = 0; m < 48; ++m)
            acc += fc[m0 + m] * Wq[(size_t)(m0 + m) * HIDDEN + col];
        qpart[seg][col] = acc;
    }
    __syncthreads();
    if (tid < HIDDEN)
        qv[tid] = ((qpart[0][tid] + qpart[1][tid]) + (qpart[2][tid] + qpart[3][tid]))
                + ((qpart[4][tid] + qpart[5][tid]) + (qpart[6][tid] + qpart[7][tid]));
    __syncthreads();

    // ---- Phase 2: qk rows; 32 half-waves x 4 rows, coalesced float4 ----
    {
        const int hw0 = tid >> 5;              // 0..31
        const float4 qv4 = *(const float4*)(&qv[sub << 2]);
        #pragma unroll
        for (int k = 0; k < 4; ++k) {
            const int row = hw0 + (k << 5);
            const float4 wk4 = *(const float4*)(Wk + (size_t)row * HIDDEN + (sub << 2));
            float p = wk4.x * qv4.x + wk4.y * qv4.y + wk4.z * qv4.z + wk4.w * qv4.w;
            #pragma unroll
            for (int off = 16; off >= 1; off >>= 1)
                p += __shfl_xor(p, off, 64);   // off<=16 stays within 32-lane half
            if (sub == 0) qks[row] = p * 0.08838834764831845f;
        }
    }
    __syncthreads();

    // ---- Phase 3: streaming online softmax + weighted sum over X ----
    const int wavesPerBlock = MAIN_THREADS >> 6;          // 16
    const int gw  = blockIdx.x * wavesPerBlock + (tid >> 6);
    const int vhw = gw * 2 + half;
    const int T   = gridDim.x * wavesPerBlock * 2;        // 16384 half-waves

    const float4 qkv = *(const float4*)(&qks[sub << 2]);

    float m = -INFINITY, s = 0.f;
    float g0 = 0.f, g1 = 0.f, g2 = 0.f, g3 = 0.f;

    for (int r = vhw; r < n; r += T) {
        const float4 xv = *(const float4*)(X + (size_t)r * HIDDEN + (sub << 2));
        float p = xv.x * qkv.x + xv.y * qkv.y + xv.z * qkv.z + xv.w * qkv.w;
        #pragma unroll
        for (int off = 16; off >= 1; off >>= 1)
            p += __shfl_xor(p, off, 64);
        const float maskv = ((bmap[r >> 5] >> (r & 31)) & 1u) ? 0.f : 1.f;
        const float u  = p + maskv;
        const float mn    = fmaxf(m, u);
        const float scale = __expf(m - mn);   // exp(-inf)=0 on first iter
        const float w     = __expf(u - mn);
        s  = s  * scale + w;
        g0 = g0 * scale + w * xv.x;
        g1 = g1 * scale + w * xv.y;
        g2 = g2 * scale + w * xv.z;
        g3 = g3 * scale + w * xv.w;
        m  = mn;
    }

    // ---- block combine: 32 half-waves -> 1 partial ----
    const int hw = tid >> 5;
    *(float4*)(&g_all[hw * HIDDEN + (sub << 2)]) = make_float4(g0, g1, g2, g3);
    if (sub == 0) { m_arr[hw] = m; s_arr[hw] = s; }
    __syncthreads();

    float mb = m_arr[0];
    #pragma unroll
    for (int h = 1; h < 32; ++h) mb = fmaxf(mb, m_arr[h]);

    if (tid < HIDDEN) {
        float G = 0.f;
        #pragma unroll 4
        for (int h = 0; h < 32; ++h)
            G += g_all[h * HIDDEN + tid] * __expf(m_arr[h] - mb);
        Gb[blockIdx.x * HIDDEN + tid] = G;
    } else if (tid == HIDDEN) {
        float S = 0.f;
        #pragma unroll
        for (int h = 0; h < 32; ++h) S += s_arr[h] * __expf(m_arr[h] - mb);
        Sb[blockIdx.x] = S;
        Mb[blockIdx.x] = mb;
    }

    // ---- Publish: syncthreads drains all waves' stores to L2; ONE release
    //      store (single wbl2) makes them LLC-visible + sets the sentinel. ----
    __syncthreads();
    if (tid == 0) {
        __hip_atomic_store(&flag64[blockIdx.x], FLAG_PAIR,
                           __ATOMIC_RELEASE, __HIP_MEMORY_SCOPE_AGENT);
    }

    if (blockIdx.x != MAIN_BLOCKS - 1) return;

    // =======================================================================
    // Finisher (block 511): wave 0 spins on 512 sentinels (8/lane), then the
    // whole block fences once and merges the partials + output GEMVs.
    // =======================================================================
    if (tid < 64) {
        #pragma unroll
        for (int k = 0; k < MAIN_BLOCKS / 64; ++k) {
            const int b = tid + (k << 6);
            while (__hip_atomic_load(&flag64[b], __ATOMIC_ACQUIRE,
                                     __HIP_MEMORY_SCOPE_AGENT) != FLAG_PAIR) {
                __builtin_amdgcn_s_sleep(4);
            }
        }
    }
    __syncthreads();
    __threadfence();   // block-local cost (16 waves): invalidate stale L1/L2 lines

    // global max over 512 block maxima
    const float mt = (tid < MAIN_BLOCKS) ? Mb[tid] : -INFINITY;
    fin_red[tid] = mt; __syncthreads();
    for (int st = 512; st >= 1; st >>= 1) {
        if (tid < st) fin_red[tid] = fmaxf(fin_red[tid], fin_red[tid + st]);
        __syncthreads();
    }
    const float M = fin_red[0];
    __syncthreads();

    // per-block scale + global softmax denominator
    float ls = 0.f;
    if (tid < MAIN_BLOCKS) {
        const float eb = __expf(mt - M); fin_e[tid] = eb; ls = Sb[tid] * eb;
    }
    fin_red[tid] = ls; __syncthreads();
    for (int st = 512; st >= 1; st >>= 1) {
        if (tid < st) fin_red[tid] += fin_red[tid + st];
        __syncthreads();
    }
    const float S = fin_red[0];
    __syncthreads();

    const int col = tid & (HIDDEN - 1);
    const int seg = tid >> 7;               // 0..7

    // pvec[col] = sum_b Gb[b,col]*e[b] / S ; 8 segments x 64 blocks
    {
        const int b0 = seg * (MAIN_BLOCKS / 8);
        float acc = 0.f;
        #pragma unroll 8
        for (int b = 0; b < MAIN_BLOCKS / 8; ++b)
            acc += Gb[(size_t)(b0 + b) * HIDDEN + col] * fin_e[b0 + b];
        qpart[seg][col] = acc;
    }
    __syncthreads();
    if (tid < HIDDEN)
        qv[tid] = (((qpart[0][tid] + qpart[1][tid]) + (qpart[2][tid] + qpart[3][tid]))
                 + ((qpart[4][tid] + qpart[5][tid]) + (qpart[6][tid] + qpart[7][tid]))) / S;
    __syncthreads();

    // h[col] = sum_m pvec[m]*Wv[m,col] ; 8 segments x 16 rows
    {
        const int m0 = seg * 16;
        float acc = 0.f;
        #pragma unroll
        for (int m2 = 0; m2 < 16; ++m2)
            acc += qv[m0 + m2] * Wv[(size_t)(m0 + m2) * HIDDEN + col];
        qpart[seg][col] = acc;
    }
    __syncthreads();
    if (tid < HIDDEN)
        qks[tid] = ((qpart[0][tid] + qpart[1][tid]) + (qpart[2][tid] + qpart[3][tid]))
                 + ((qpart[4][tid] + qpart[5][tid]) + (qpart[6][tid] + qpart[7][tid]));
    __syncthreads();

    // out[col] = sum_m h[m]*Wo[m,col]
    {
        const int m0 = seg * 16;
        float acc = 0.f;
        #pragma unroll
        for (int m2 = 0; m2 < 16; ++m2)
            acc += qks[m0 + m2] * Wo[(size_t)(m0 + m2) * HIDDEN + col];
        qpart[seg][col] = acc;
    }
    __syncthreads();
    if (tid < HIDDEN)
        out[tid] = ((qpart[0][tid] + qpart[1][tid]) + (qpart[2][tid] + qpart[3][tid]))
                 + ((qpart[4][tid] + qpart[5][tid]) + (qpart[6][tid] + qpart[7][tid]));
}

// ---------------------------------------------------------------------------
extern "C" void kernel_launch(void* const* d_in, const int* in_sizes, int n_in,
                              void* d_out, int out_size, void* d_ws, size_t ws_size,
                              hipStream_t stream)
{
    const float* X       = (const float*)d_in[0];
    const float* x       = (const float*)d_in[1];
    const float* Wq      = (const float*)d_in[2];
    const float* Wk      = (const float*)d_in[3];
    const float* Wv      = (const float*)d_in[4];
    const float* Wo      = (const float*)d_in[5];
    const int*   visited = (const int*)d_in[6];
    const int*   startp  = (const int*)d_in[7];
    const int*   prevp   = (const int*)d_in[8];

    const int n  = in_sizes[0] / HIDDEN;   // 200000
    const int nv = in_sizes[6];            // 1024

    float* ws = (float*)d_ws;
    float* Mb = ws + 128;
    float* Sb = Mb + MAIN_BLOCKS;
    float* Gb = Sb + MAIN_BLOCKS;                        // MAIN_BLOCKS*128
    // Gb ends at float offset 128+512+512+65536 = 66688 -> byte 266752 (8B-aligned)
    unsigned long long* flag64 =
        (unsigned long long*)(Gb + (size_t)MAIN_BLOCKS * HIDDEN);

    fused_all<<<MAIN_BLOCKS, MAIN_THREADS, 0, stream>>>(
        X, x, Wq, Wk, Wv, Wo, visited, nv, startp, prevp,
        Mb, Sb, Gb, flag64, (float*)d_out, n);
}

// Round 4
// 180.281 us; speedup vs baseline: 1.7452x; 1.0563x over previous
//
#include <hip/hip_runtime.h>
#include <math.h>

#define HIDDEN 128
#define MAIN_BLOCKS 512
#define MAIN_THREADS 1024
#define MAX_BMAP_WORDS 6272   // 200704 bits >= 200000 nodes
#define FLAG_MAGIC 0x13579BDFu
// 64-bit sentinel: low=MAGIC, high=~MAGIC. No uniform 32-bit poison P can
// fake it (needs P==MAGIC && P==~MAGIC), so flags are init-free in poisoned ws.
#define FLAG_PAIR ((((unsigned long long)(~FLAG_MAGIC)) << 32) | (unsigned long long)FLAG_MAGIC)

// ---------------------------------------------------------------------------
// Single fused kernel (512 blocks x 1024 threads), ZERO cache-maintenance sync:
//   Round-2/3 lesson: agent-scope RELEASE (buffer_wbl2) / ACQUIRE (buffer_inv)
//   cost ~100ns each and serialize at the per-XCD L2; O(blocks) of them = the
//   52us tail rocprof showed (Occupancy 31% => ~23us stream + ~52us tail).
//   Fix: partials are stored with RELAXED+AGENT atomics (global_store sc1 =
//   write-through to LLC, no wbl2). __syncthreads drains each wave's vmcnt
//   (measured compiler behavior), so after the barrier all partials are
//   device-visible; the flag store is then also a RELAXED sc1 store.
//   The finisher spins with RELAXED sc1 loads (no buffer_inv per poll) and
//   reads partials with RELAXED sc1 loads (bypass stale L1/L2), so no fence
//   instruction appears anywhere on the critical path.
// ---------------------------------------------------------------------------
__global__ __launch_bounds__(MAIN_THREADS) void fused_all(
    const float* __restrict__ X, const float* __restrict__ x,
    const float* __restrict__ Wq, const float* __restrict__ Wk,
    const float* __restrict__ Wv, const float* __restrict__ Wo,
    const int* __restrict__ visited, int nv,
    const int* __restrict__ startp, const int* __restrict__ prevp,
    float* __restrict__ Mb, float* __restrict__ Sb, float* __restrict__ Gb,
    unsigned long long* __restrict__ flag64,
    float* __restrict__ out, int n)
{
    __shared__ unsigned bmap[MAX_BMAP_WORDS];   // 25088 B
    __shared__ float fc[384];
    __shared__ float qpart[8][HIDDEN];          // 4 KB (reused by finisher)
    __shared__ float qv[HIDDEN];                // q, later pvec
    __shared__ float qks[HIDDEN];               // qk, later hvec
    __shared__ float m_arr[32];
    __shared__ float s_arr[32];
    __shared__ float g_all[32 * HIDDEN];        // 16 KB
    __shared__ float fin_red[MAIN_THREADS];     // 4 KB (finisher reductions)
    __shared__ float fin_e[MAIN_BLOCKS];        // 2 KB
    // total ~53.4 KB -> 2 blocks/CU (wave-limited: 16 waves/block)

    const int tid  = threadIdx.x;
    const int lane = tid & 63;
    const int sub  = lane & 31;
    const int half = (lane >> 5) & 1;

    // ---- Phase 0: issue fc global loads early, zero bitmap meanwhile ----
    const int nwords = (n + 31) >> 5;
    float fcv = 0.f;
    if (tid < 384) {
        if (tid < 128)      fcv = x[tid];
        else if (tid < 256) fcv = X[(size_t)startp[0] * HIDDEN + (tid - 128)];
        else                fcv = X[(size_t)prevp[0]  * HIDDEN + (tid - 256)];
    }
    for (int w = tid; w < nwords; w += MAIN_THREADS) bmap[w] = 0u;
    if (tid < 384) fc[tid] = fcv;
    __syncthreads();

    // ---- Phase 1: visited scatter (dup-safe) + q partials (q = fc @ Wq) ----
    for (int i = tid; i < nv; i += MAIN_THREADS) {
        const int v = visited[i];
        atomicOr(&bmap[v >> 5], 1u << (v & 31));
    }
    {
        const int col = tid & (HIDDEN - 1);
        const int seg = tid >> 7;              // 0..7, 48 m-rows each
        const int m0  = seg * 48;
        float acc = 0.f;
        #pragma unroll 8
        for (int m = 0; m < 48; ++m)
            acc += fc[m0 + m] * Wq[(size_t)(m0 + m) * HIDDEN + col];
        qpart[seg][col] = acc;
    }
    __syncthreads();
    if (tid < HIDDEN)
        qv[tid] = ((qpart[0][tid] + qpart[1][tid]) + (qpart[2][tid] + qpart[3][tid]))
                + ((qpart[4][tid] + qpart[5][tid]) + (qpart[6][tid] + qpart[7][tid]));
    __syncthreads();

    // ---- Phase 2: qk rows; 32 half-waves x 4 rows, coalesced float4 ----
    {
        const int hw0 = tid >> 5;              // 0..31
        const float4 qv4 = *(const float4*)(&qv[sub << 2]);
        #pragma unroll
        for (int k = 0; k < 4; ++k) {
            const int row = hw0 + (k << 5);
            const float4 wk4 = *(const float4*)(Wk + (size_t)row * HIDDEN + (sub << 2));
            float p = wk4.x * qv4.x + wk4.y * qv4.y + wk4.z * qv4.z + wk4.w * qv4.w;
            #pragma unroll
            for (int off = 16; off >= 1; off >>= 1)
                p += __shfl_xor(p, off, 64);   // off<=16 stays within 32-lane half
            if (sub == 0) qks[row] = p * 0.08838834764831845f;
        }
    }
    __syncthreads();

    // ---- Phase 3: streaming online softmax + weighted sum over X ----
    const int wavesPerBlock = MAIN_THREADS >> 6;          // 16
    const int gw  = blockIdx.x * wavesPerBlock + (tid >> 6);
    const int vhw = gw * 2 + half;
    const int T   = gridDim.x * wavesPerBlock * 2;        // 16384 half-waves

    const float4 qkv = *(const float4*)(&qks[sub << 2]);

    float m = -INFINITY, s = 0.f;
    float g0 = 0.f, g1 = 0.f, g2 = 0.f, g3 = 0.f;

    for (int r = vhw; r < n; r += T) {
        const float4 xv = *(const float4*)(X + (size_t)r * HIDDEN + (sub << 2));
        float p = xv.x * qkv.x + xv.y * qkv.y + xv.z * qkv.z + xv.w * qkv.w;
        #pragma unroll
        for (int off = 16; off >= 1; off >>= 1)
            p += __shfl_xor(p, off, 64);
        const float maskv = ((bmap[r >> 5] >> (r & 31)) & 1u) ? 0.f : 1.f;
        const float u  = p + maskv;
        const float mn    = fmaxf(m, u);
        const float scale = __expf(m - mn);   // exp(-inf)=0 on first iter
        const float w     = __expf(u - mn);
        s  = s  * scale + w;
        g0 = g0 * scale + w * xv.x;
        g1 = g1 * scale + w * xv.y;
        g2 = g2 * scale + w * xv.z;
        g3 = g3 * scale + w * xv.w;
        m  = mn;
    }

    // ---- block combine: 32 half-waves -> 1 partial ----
    const int hw = tid >> 5;
    *(float4*)(&g_all[hw * HIDDEN + (sub << 2)]) = make_float4(g0, g1, g2, g3);
    if (sub == 0) { m_arr[hw] = m; s_arr[hw] = s; }
    __syncthreads();

    float mb = m_arr[0];
    #pragma unroll
    for (int h = 1; h < 32; ++h) mb = fmaxf(mb, m_arr[h]);

    // ---- Publish partials as RELAXED+AGENT (sc1, LLC-visible at ack) ----
    if (tid < HIDDEN) {
        float G = 0.f;
        #pragma unroll 4
        for (int h = 0; h < 32; ++h)
            G += g_all[h * HIDDEN + tid] * __expf(m_arr[h] - mb);
        __hip_atomic_store(&Gb[blockIdx.x * HIDDEN + tid], G,
                           __ATOMIC_RELAXED, __HIP_MEMORY_SCOPE_AGENT);
    } else if (tid == HIDDEN) {
        float S = 0.f;
        #pragma unroll
        for (int h = 0; h < 32; ++h) S += s_arr[h] * __expf(m_arr[h] - mb);
        __hip_atomic_store(&Sb[blockIdx.x], S,
                           __ATOMIC_RELAXED, __HIP_MEMORY_SCOPE_AGENT);
        __hip_atomic_store(&Mb[blockIdx.x], mb,
                           __ATOMIC_RELAXED, __HIP_MEMORY_SCOPE_AGENT);
    }

    // barrier: every wave drains vmcnt(0) before s_barrier (measured compiler
    // behavior) => all sc1 partial stores are device-visible past this point.
    __syncthreads();
    if (tid == 0) {
        __hip_atomic_store(&flag64[blockIdx.x], FLAG_PAIR,
                           __ATOMIC_RELAXED, __HIP_MEMORY_SCOPE_AGENT);
    }

    if (blockIdx.x != MAIN_BLOCKS - 1) return;

    // =======================================================================
    // Finisher (block 511): wave 0 spins on 512 sentinels with RELAXED sc1
    // loads (no buffer_inv). In-order wave + branch on the loaded value means
    // nothing after the loop issues before the flag is seen; __syncthreads is
    // the compiler/HW barrier; partial reads below are sc1 so stale L1/L2
    // lines are never consulted.
    // =======================================================================
    if (tid < 64) {
        #pragma unroll
        for (int k = 0; k < MAIN_BLOCKS / 64; ++k) {
            const int b = tid + (k << 6);
            while (__hip_atomic_load(&flag64[b], __ATOMIC_RELAXED,
                                     __HIP_MEMORY_SCOPE_AGENT) != FLAG_PAIR) {
                __builtin_amdgcn_s_sleep(2);
            }
        }
    }
    __syncthreads();

    // global max over 512 block maxima
    const float mt = (tid < MAIN_BLOCKS)
        ? __hip_atomic_load(&Mb[tid], __ATOMIC_RELAXED, __HIP_MEMORY_SCOPE_AGENT)
        : -INFINITY;
    fin_red[tid] = mt; __syncthreads();
    for (int st = 512; st >= 1; st >>= 1) {
        if (tid < st) fin_red[tid] = fmaxf(fin_red[tid], fin_red[tid + st]);
        __syncthreads();
    }
    const float M = fin_red[0];
    __syncthreads();

    // per-block scale + global softmax denominator
    float ls = 0.f;
    if (tid < MAIN_BLOCKS) {
        const float eb = __expf(mt - M);
        fin_e[tid] = eb;
        ls = __hip_atomic_load(&Sb[tid], __ATOMIC_RELAXED,
                               __HIP_MEMORY_SCOPE_AGENT) * eb;
    }
    fin_red[tid] = ls; __syncthreads();
    for (int st = 512; st >= 1; st >>= 1) {
        if (tid < st) fin_red[tid] += fin_red[tid + st];
        __syncthreads();
    }
    const float S = fin_red[0];
    __syncthreads();

    const int col = tid & (HIDDEN - 1);
    const int seg = tid >> 7;               // 0..7

    // pvec[col] = sum_b Gb[b,col]*e[b] / S ; 8 segments x 64 blocks
    {
        const int b0 = seg * (MAIN_BLOCKS / 8);
        float acc = 0.f;
        #pragma unroll 8
        for (int b = 0; b < MAIN_BLOCKS / 8; ++b)
            acc += __hip_atomic_load(&Gb[(size_t)(b0 + b) * HIDDEN + col],
                                     __ATOMIC_RELAXED, __HIP_MEMORY_SCOPE_AGENT)
                   * fin_e[b0 + b];
        qpart[seg][col] = acc;
    }
    __syncthreads();
    if (tid < HIDDEN)
        qv[tid] = (((qpart[0][tid] + qpart[1][tid]) + (qpart[2][tid] + qpart[3][tid]))
                 + ((qpart[4][tid] + qpart[5][tid]) + (qpart[6][tid] + qpart[7][tid]))) / S;
    __syncthreads();

    // h[col] = sum_m pvec[m]*Wv[m,col] ; 8 segments x 16 rows
    {
        const int m0 = seg * 16;
        float acc = 0.f;
        #pragma unroll
        for (int m2 = 0; m2 < 16; ++m2)
            acc += qv[m0 + m2] * Wv[(size_t)(m0 + m2) * HIDDEN + col];
        qpart[seg][col] = acc;
    }
    __syncthreads();
    if (tid < HIDDEN)
        qks[tid] = ((qpart[0][tid] + qpart[1][tid]) + (qpart[2][tid] + qpart[3][tid]))
                 + ((qpart[4][tid] + qpart[5][tid]) + (qpart[6][tid] + qpart[7][tid]));
    __syncthreads();

    // out[col] = sum_m h[m]*Wo[m,col]
    {
        const int m0 = seg * 16;
        float acc = 0.f;
        #pragma unroll
        for (int m2 = 0; m2 < 16; ++m2)
            acc += qks[m0 + m2] * Wo[(size_t)(m0 + m2) * HIDDEN + col];
        qpart[seg][col] = acc;
    }
    __syncthreads();
    if (tid < HIDDEN)
        out[tid] = ((qpart[0][tid] + qpart[1][tid]) + (qpart[2][tid] + qpart[3][tid]))
                 + ((qpart[4][tid] + qpart[5][tid]) + (qpart[6][tid] + qpart[7][tid]));
}

// ---------------------------------------------------------------------------
extern "C" void kernel_launch(void* const* d_in, const int* in_sizes, int n_in,
                              void* d_out, int out_size, void* d_ws, size_t ws_size,
                              hipStream_t stream)
{
    const float* X       = (const float*)d_in[0];
    const float* x       = (const float*)d_in[1];
    const float* Wq      = (const float*)d_in[2];
    const float* Wk      = (const float*)d_in[3];
    const float* Wv      = (const float*)d_in[4];
    const float* Wo      = (const float*)d_in[5];
    const int*   visited = (const int*)d_in[6];
    const int*   startp  = (const int*)d_in[7];
    const int*   prevp   = (const int*)d_in[8];

    const int n  = in_sizes[0] / HIDDEN;   // 200000
    const int nv = in_sizes[6];            // 1024

    float* ws = (float*)d_ws;
    float* Mb = ws + 128;
    float* Sb = Mb + MAIN_BLOCKS;
    float* Gb = Sb + MAIN_BLOCKS;                        // MAIN_BLOCKS*128
    // Gb ends at float offset 128+512+512+65536 = 66688 -> byte 266752 (8B-aligned)
    unsigned long long* flag64 =
        (unsigned long long*)(Gb + (size_t)MAIN_BLOCKS * HIDDEN);

    fused_all<<<MAIN_BLOCKS, MAIN_THREADS, 0, stream>>>(
        X, x, Wq, Wk, Wv, Wo, visited, nv, startp, prevp,
        Mb, Sb, Gb, flag64, (float*)d_out, n);
}